// Round 1
// baseline (670.017 us; speedup 1.0000x reference)
//
#include <hip/hip_runtime.h>
#include <math.h>

#define DD 128            // feature dim
#define KNB 20            // neighbors per node
#define K3 384            // 3*D
#define MTILE 32          // rows per GEMM block
#define APAD 388          // 384+4 pad: ty-rows hit banks {0,8,16,24}
#define HPAD 132          // 128+4 pad, same property

// ---------------------------------------------------------------------------
// Kernel C: constant vector  c[d] = b2[d] + sum_i cos(tb[i]) * W2[(2D+i)*D + d]
// (src time embedding is node-independent)
// ---------------------------------------------------------------------------
__global__ __launch_bounds__(DD) void const_kernel(
    const float* __restrict__ tb, const float* __restrict__ W2,
    const float* __restrict__ b2, float* __restrict__ cvec)
{
    int d = threadIdx.x;
    float acc = b2[d];
    #pragma unroll 8
    for (int i = 0; i < DD; ++i) {
        acc = fmaf(cosf(tb[i]), W2[(size_t)(2 * DD + i) * DD + d], acc);
    }
    cvec[d] = acc;
}

// ---------------------------------------------------------------------------
// Kernel A: per-node aggregation.
// AGG[n] = [ sum_k NF[nbr], sum_k cos(dt*w+b), sum_k EF[edge] ]   (length 384)
// One 128-thread block per node; gathers are 512B-coalesced rows; the index /
// time loads are wave-uniform (blockIdx-based) -> scalar loads.
// ---------------------------------------------------------------------------
__global__ __launch_bounds__(DD) void agg_kernel(
    const float* __restrict__ nodef, const float* __restrict__ ts,
    const float* __restrict__ edgef, const int* __restrict__ neighbors,
    const int* __restrict__ edge_idxs, const float* __restrict__ edge_times,
    const float* __restrict__ tw, const float* __restrict__ tb,
    float* __restrict__ agg)
{
    const int n = blockIdx.x;
    const int t = threadIdx.x;
    const float w = tw[t];
    const float b = tb[t];
    const float tn = ts[n];
    const int*   nb = neighbors  + (size_t)n * KNB;
    const int*   eg = edge_idxs  + (size_t)n * KNB;
    const float* et = edge_times + (size_t)n * KNB;

    float an = 0.f, at = 0.f, ae = 0.f;
    #pragma unroll
    for (int k = 0; k < KNB; ++k) {
        int ni = nb[k];
        int ei = eg[k];
        float dt = tn - et[k];
        an += nodef[(size_t)ni * DD + t];
        ae += edgef[(size_t)ei * DD + t];
        at += cosf(fmaf(dt, w, b));
    }
    float* o = agg + (size_t)n * K3;
    o[t]          = an;
    o[DD + t]     = at;
    o[2 * DD + t] = ae;
}

// ---------------------------------------------------------------------------
// Kernel B: fused GEMM.
// out[n] = relu(AGG[n]@W1 + 20*b1) @ W2[0:128] + NF[n] @ W2[128:256] + cvec
// 256 threads = 16 tx (8 cols each) x 16 ty (2 rows each); 32 rows/block.
// ---------------------------------------------------------------------------
__device__ __forceinline__ void mm16(const float4 a0, const float4 a1,
                                     const float4* __restrict__ Bv,
                                     int kkbase, int tx, float acc[2][8])
{
    float aa0[4] = {a0.x, a0.y, a0.z, a0.w};
    float aa1[4] = {a1.x, a1.y, a1.z, a1.w};
    #pragma unroll
    for (int u = 0; u < 4; ++u) {
        float4 b0 = Bv[(size_t)(kkbase + u) * 32 + 2 * tx];
        float4 b1 = Bv[(size_t)(kkbase + u) * 32 + 2 * tx + 1];
        float bb[8] = {b0.x, b0.y, b0.z, b0.w, b1.x, b1.y, b1.z, b1.w};
        #pragma unroll
        for (int j = 0; j < 8; ++j) {
            acc[0][j] = fmaf(aa0[u], bb[j], acc[0][j]);
            acc[1][j] = fmaf(aa1[u], bb[j], acc[1][j]);
        }
    }
}

__global__ __launch_bounds__(256) void fused_gemm(
    const float* __restrict__ agg, const float* __restrict__ nodef,
    const float* __restrict__ W1, const float* __restrict__ b1,
    const float* __restrict__ W2, const float* __restrict__ cvec,
    float* __restrict__ out, int N)
{
    __shared__ float As[MTILE * APAD];   // 49664 B; reused as Hs[MTILE*HPAD] in phase 2

    const int tid  = threadIdx.x;
    const int row0 = blockIdx.x * MTILE;

    // stage AGG tile [32][384] -> LDS (padded rows)
    {
        const float4* ag4 = (const float4*)agg;
        #pragma unroll
        for (int i = tid; i < MTILE * 96; i += 256) {
            int r = i / 96, c = i - r * 96;
            float4 v = make_float4(0.f, 0.f, 0.f, 0.f);
            int row = row0 + r;
            if (row < N) v = ag4[(size_t)row * 96 + c];
            *(float4*)&As[r * APAD + 4 * c] = v;
        }
    }
    __syncthreads();

    const int tx = tid & 15;    // cols 8*tx .. 8*tx+7
    const int ty = tid >> 4;    // rows 2*ty, 2*ty+1

    const float4* W1v = (const float4*)W1;
    const float4* W2v = (const float4*)W2;

    // ---- phase 1: H = AGG @ W1 ----
    float acc[2][8];
    #pragma unroll
    for (int j = 0; j < 8; ++j) { acc[0][j] = 0.f; acc[1][j] = 0.f; }

    const float* a0p = &As[(2 * ty) * APAD];
    const float* a1p = &As[(2 * ty + 1) * APAD];
    for (int kk = 0; kk < K3; kk += 4) {
        float4 a0 = *(const float4*)(a0p + kk);
        float4 a1 = *(const float4*)(a1p + kk);
        mm16(a0, a1, W1v, kk, tx, acc);
    }

    // ---- bias + relu, store H into reused LDS ----
    __syncthreads();   // everyone done reading As
    float* Hs = As;
    #pragma unroll
    for (int r = 0; r < 2; ++r) {
        #pragma unroll
        for (int j = 0; j < 8; ++j) {
            float h = fmaf((float)KNB, b1[8 * tx + j], acc[r][j]);
            h = h > 0.f ? h : 0.f;
            Hs[(2 * ty + r) * HPAD + 8 * tx + j] = h;
        }
    }
    __syncthreads();

    // ---- phase 2: out = H @ W2[0:128] + NF @ W2[128:256] + cvec ----
    float acc2[2][8];
    #pragma unroll
    for (int j = 0; j < 8; ++j) {
        float cv = cvec[8 * tx + j];
        acc2[0][j] = cv;
        acc2[1][j] = cv;
    }

    const float* h0p = &Hs[(2 * ty) * HPAD];
    const float* h1p = &Hs[(2 * ty + 1) * HPAD];
    for (int kk = 0; kk < DD; kk += 4) {
        float4 a0 = *(const float4*)(h0p + kk);
        float4 a1 = *(const float4*)(h1p + kk);
        mm16(a0, a1, W2v, kk, tx, acc2);
    }

    // NF part: A rows straight from global (L1/L2-hot within the block)
    {
        int r0 = row0 + 2 * ty;
        int r1 = r0 + 1;
        const float4* nfv = (const float4*)nodef;
        size_t cr0 = (size_t)(r0 < N ? r0 : (N - 1)) * 32;   // clamp; rows >= N never stored
        size_t cr1 = (size_t)(r1 < N ? r1 : (N - 1)) * 32;
        for (int kk = 0; kk < DD; kk += 4) {
            float4 a0 = nfv[cr0 + (kk >> 2)];
            float4 a1 = nfv[cr1 + (kk >> 2)];
            mm16(a0, a1, W2v, DD + kk, tx, acc2);
        }
    }

    // ---- store ----
    float4* out4 = (float4*)out;
    #pragma unroll
    for (int r = 0; r < 2; ++r) {
        int row = row0 + 2 * ty + r;
        if (row < N) {
            float4 o0 = make_float4(acc2[r][0], acc2[r][1], acc2[r][2], acc2[r][3]);
            float4 o1 = make_float4(acc2[r][4], acc2[r][5], acc2[r][6], acc2[r][7]);
            out4[(size_t)row * 32 + 2 * tx]     = o0;
            out4[(size_t)row * 32 + 2 * tx + 1] = o1;
        }
    }
}

// ---------------------------------------------------------------------------
extern "C" void kernel_launch(void* const* d_in, const int* in_sizes, int n_in,
                              void* d_out, int out_size, void* d_ws, size_t ws_size,
                              hipStream_t stream)
{
    const float* nodef      = (const float*)d_in[0];
    const float* ts         = (const float*)d_in[1];
    const float* edgef      = (const float*)d_in[2];
    const int*   neighbors  = (const int*)d_in[3];
    const int*   edge_idxs  = (const int*)d_in[4];
    const float* edge_times = (const float*)d_in[5];
    const float* tw         = (const float*)d_in[6];
    const float* tb         = (const float*)d_in[7];
    const float* W1         = (const float*)d_in[8];
    const float* b1         = (const float*)d_in[9];
    const float* W2         = (const float*)d_in[10];
    const float* b2         = (const float*)d_in[11];
    float*       out        = (float*)d_out;

    const int N = in_sizes[1];          // 30000

    float* agg  = (float*)d_ws;                       // [N, 384]
    float* cvec = agg + (size_t)N * K3;               // [128]

    hipLaunchKernelGGL(const_kernel, dim3(1), dim3(DD), 0, stream,
                       tb, W2, b2, cvec);
    hipLaunchKernelGGL(agg_kernel, dim3(N), dim3(DD), 0, stream,
                       nodef, ts, edgef, neighbors, edge_idxs, edge_times,
                       tw, tb, agg);
    const int gb = (N + MTILE - 1) / MTILE;
    hipLaunchKernelGGL(fused_gemm, dim3(gb), dim3(256), 0, stream,
                       agg, nodef, W1, b1, W2, cvec, out, N);
}

// Round 2
// 520.796 us; speedup vs baseline: 1.2865x; 1.2865x over previous
//
#include <hip/hip_runtime.h>
#include <math.h>

#define DD 128            // feature dim
#define KNB 20            // neighbors per node
#define K3 384            // 3*D

typedef unsigned short u16;
typedef __attribute__((ext_vector_type(8))) short short8;   // 8 bf16 = 4 VGPRs
typedef __attribute__((ext_vector_type(4))) float f32x4;

// f32 -> bf16 round-to-nearest-even
static __device__ __forceinline__ u16 f2bf(float x) {
    union { float f; unsigned u; } v; v.f = x;
    unsigned r = v.u + 0x7fffu + ((v.u >> 16) & 1u);
    return (u16)(r >> 16);
}

// ---------------------------------------------------------------------------
// cvec[d] = b2[d] + sum_i cos(tb[i]) * W2[(2D+i)*D + d]   (src time emb const)
// ---------------------------------------------------------------------------
__global__ __launch_bounds__(DD) void const_kernel(
    const float* __restrict__ tb, const float* __restrict__ W2,
    const float* __restrict__ b2, float* __restrict__ cvec)
{
    int d = threadIdx.x;
    float acc = b2[d];
    #pragma unroll 8
    for (int i = 0; i < DD; ++i)
        acc = fmaf(cosf(tb[i]), W2[(size_t)(2 * DD + i) * DD + d], acc);
    cvec[d] = acc;
}

// ---------------------------------------------------------------------------
// Pack W1 (384x128) and W2 rows 0..255 into MFMA B-fragment order, bf16.
// For 16x16x32: lane L holds B[k0 + (L>>4)*8 + j][ct*16 + (L&15)], j=0..7,
// stored contiguously (16B per lane) at [ktile][ct][L][8].
// W1p: 12 ktiles; W2p: part 0 (H, rows 0..127) then part 1 (NF, rows 128..255),
// 4 ktiles each.
// ---------------------------------------------------------------------------
__global__ __launch_bounds__(256) void pack_w(
    const float* __restrict__ W1, const float* __restrict__ W2,
    u16* __restrict__ W1p, u16* __restrict__ W2p)
{
    int t = blockIdx.x * 256 + threadIdx.x;
    if (t < 6144) {                       // W1: 12 * 8 * 64
        int L = t & 63;
        int ct = (t >> 6) & 7;
        int kt = t >> 9;
        int n  = ct * 16 + (L & 15);
        int kb = kt * 32 + (L >> 4) * 8;
        u16* d = W1p + (size_t)t * 8;
        #pragma unroll
        for (int j = 0; j < 8; ++j) d[j] = f2bf(W1[(size_t)(kb + j) * DD + n]);
    } else if (t < 10240) {               // W2 parts 0,1: 2 * 4 * 8 * 64
        int u = t - 6144;
        int L = u & 63;
        int ct = (u >> 6) & 7;
        int kt = (u >> 9) & 3;
        int part = u >> 11;
        int n  = ct * 16 + (L & 15);
        int kb = part * DD + kt * 32 + (L >> 4) * 8;
        u16* d = W2p + (size_t)u * 8;
        #pragma unroll
        for (int j = 0; j < 8; ++j) d[j] = f2bf(W2[(size_t)(kb + j) * DD + n]);
    }
}

// ---------------------------------------------------------------------------
// Kernel A: per-node aggregation -> bf16 AGG[N][384]; also bf16 copy of NF row.
// ---------------------------------------------------------------------------
__global__ __launch_bounds__(DD) void agg_kernel(
    const float* __restrict__ nodef, const float* __restrict__ ts,
    const float* __restrict__ edgef, const int* __restrict__ neighbors,
    const int* __restrict__ edge_idxs, const float* __restrict__ edge_times,
    const float* __restrict__ tw, const float* __restrict__ tb,
    u16* __restrict__ aggbf, u16* __restrict__ nfbf)
{
    const int n = blockIdx.x;
    const int t = threadIdx.x;
    const float w = tw[t];
    const float b = tb[t];
    const float tn = ts[n];
    const int*   nb = neighbors  + (size_t)n * KNB;
    const int*   eg = edge_idxs  + (size_t)n * KNB;
    const float* et = edge_times + (size_t)n * KNB;

    float an = 0.f, at = 0.f, ae = 0.f;
    #pragma unroll
    for (int k = 0; k < KNB; ++k) {
        int ni = nb[k];
        int ei = eg[k];
        float dt = tn - et[k];
        an += nodef[(size_t)ni * DD + t];
        ae += edgef[(size_t)ei * DD + t];
        at += cosf(fmaf(dt, w, b));
    }
    u16* o = aggbf + (size_t)n * K3;
    o[t]          = f2bf(an);
    o[DD + t]     = f2bf(at);
    o[2 * DD + t] = f2bf(ae);
    nfbf[(size_t)n * DD + t] = f2bf(nodef[(size_t)n * DD + t]);
}

// ---------------------------------------------------------------------------
// Fused MFMA GEMM: 32 rows/block, 256 threads = 4 waves.
// wave -> rows m0 = (wave&1)*16, col-tiles ctbase = (wave>>1)*4 (4 tiles of 16).
// Phase1: H = relu(AGG@W1 + 20*b1)  -> bf16 in LDS
// Phase2: out = H@W2[0:128] + NF@W2[128:256] + cvec
// ---------------------------------------------------------------------------
#define APITCH 392      // bf16 elems; 784B rows: 16B-aligned, stride==4 mod 32 banks
#define HPITCH 136      // 272B rows: 16B-aligned, stride==4 mod 32 banks

__global__ __launch_bounds__(256) void fused_gemm(
    const u16* __restrict__ aggbf, const u16* __restrict__ nfbf,
    const u16* __restrict__ W1p, const u16* __restrict__ W2p,
    const float* __restrict__ b1, const float* __restrict__ cvec,
    float* __restrict__ out, int N)
{
    __shared__ __align__(16) u16 As[32 * APITCH];   // 25088 B; reused for Hs+NFs

    const int tid  = threadIdx.x;
    const int lane = tid & 63;
    const int wave = tid >> 6;
    const int row0 = blockIdx.x * 32;
    const int m0     = (wave & 1) * 16;
    const int ctbase = (wave >> 1) * 4;
    const int l15  = lane & 15;
    const int quad = lane >> 4;

    // ---- stage AGG tile [32][384] bf16 -> LDS ----
    {
        const float4* ag4 = (const float4*)aggbf;   // 8 bf16 per float4
        #pragma unroll
        for (int i = 0; i < 6; ++i) {
            int idx = tid + i * 256;                // 0..1535 = 32*48
            int r = idx / 48, c = idx - r * 48;
            float4 v = make_float4(0.f, 0.f, 0.f, 0.f);
            int row = row0 + r;
            if (row < N) v = ag4[(size_t)row * 48 + c];
            *(float4*)&As[r * APITCH + c * 8] = v;
        }
    }
    __syncthreads();

    // ---- phase 1: AGG @ W1 ----
    f32x4 acc[4];
    #pragma unroll
    for (int c = 0; c < 4; ++c) acc[c] = (f32x4){0.f, 0.f, 0.f, 0.f};

    const short8* W1v = (const short8*)W1p;
    for (int kt = 0; kt < 12; ++kt) {
        short8 a = *(const short8*)&As[(m0 + l15) * APITCH + kt * 32 + quad * 8];
        #pragma unroll
        for (int c = 0; c < 4; ++c) {
            short8 b = W1v[(size_t)(kt * 8 + ctbase + c) * 64 + lane];
            acc[c] = __builtin_amdgcn_mfma_f32_16x16x32_bf16(a, b, acc[c], 0, 0, 0);
        }
    }
    __syncthreads();    // all waves done reading As

    // ---- epilogue 1: bias+relu -> Hs (bf16, reused LDS); stage NF tile ----
    u16* Hs  = As;
    u16* NFs = As + 32 * HPITCH;
    #pragma unroll
    for (int c = 0; c < 4; ++c) {
        int col = (ctbase + c) * 16 + l15;
        float bb = (float)KNB * b1[col];
        #pragma unroll
        for (int r = 0; r < 4; ++r) {
            float h = acc[c][r] + bb;               // C/D: col=lane&15, row=quad*4+r
            h = h > 0.f ? h : 0.f;
            Hs[(m0 + quad * 4 + r) * HPITCH + col] = f2bf(h);
        }
    }
    {
        const float4* nf4 = (const float4*)nfbf;
        #pragma unroll
        for (int i = 0; i < 2; ++i) {
            int idx = tid + i * 256;                // 0..511 = 32*16
            int r = idx >> 4, c = idx & 15;
            float4 v = make_float4(0.f, 0.f, 0.f, 0.f);
            int row = row0 + r;
            if (row < N) v = nf4[(size_t)row * 16 + c];
            *(float4*)&NFs[r * HPITCH + c * 8] = v;
        }
    }
    __syncthreads();

    // ---- phase 2: H@W2a + NF@W2b + cvec ----
    f32x4 acc2[4];
    #pragma unroll
    for (int c = 0; c < 4; ++c) {
        float cv = cvec[(ctbase + c) * 16 + l15];
        acc2[c] = (f32x4){cv, cv, cv, cv};
    }
    const short8* W2v = (const short8*)W2p;
    for (int kt = 0; kt < 4; ++kt) {
        short8 aH = *(const short8*)&Hs[(m0 + l15) * HPITCH + kt * 32 + quad * 8];
        #pragma unroll
        for (int c = 0; c < 4; ++c) {
            short8 b = W2v[(size_t)(kt * 8 + ctbase + c) * 64 + lane];
            acc2[c] = __builtin_amdgcn_mfma_f32_16x16x32_bf16(aH, b, acc2[c], 0, 0, 0);
        }
        short8 aN = *(const short8*)&NFs[(m0 + l15) * HPITCH + kt * 32 + quad * 8];
        #pragma unroll
        for (int c = 0; c < 4; ++c) {
            short8 b = W2v[(size_t)((4 + kt) * 8 + ctbase + c) * 64 + lane];
            acc2[c] = __builtin_amdgcn_mfma_f32_16x16x32_bf16(aN, b, acc2[c], 0, 0, 0);
        }
    }

    // ---- store ----
    #pragma unroll
    for (int c = 0; c < 4; ++c) {
        int col = (ctbase + c) * 16 + l15;
        #pragma unroll
        for (int r = 0; r < 4; ++r) {
            int row = row0 + m0 + quad * 4 + r;
            if (row < N) out[(size_t)row * DD + col] = acc2[c][r];
        }
    }
}

// ---------------------------------------------------------------------------
extern "C" void kernel_launch(void* const* d_in, const int* in_sizes, int n_in,
                              void* d_out, int out_size, void* d_ws, size_t ws_size,
                              hipStream_t stream)
{
    const float* nodef      = (const float*)d_in[0];
    const float* ts         = (const float*)d_in[1];
    const float* edgef      = (const float*)d_in[2];
    const int*   neighbors  = (const int*)d_in[3];
    const int*   edge_idxs  = (const int*)d_in[4];
    const float* edge_times = (const float*)d_in[5];
    const float* tw         = (const float*)d_in[6];
    const float* tb         = (const float*)d_in[7];
    const float* W1         = (const float*)d_in[8];
    const float* b1         = (const float*)d_in[9];
    const float* W2         = (const float*)d_in[10];
    const float* b2         = (const float*)d_in[11];
    float*       out        = (float*)d_out;

    const int N = in_sizes[1];          // 30000

    u16*   aggbf = (u16*)d_ws;                          // [N*384] bf16
    u16*   nfbf  = aggbf + (size_t)N * K3;              // [N*128] bf16
    u16*   W1p   = nfbf + (size_t)N * DD;               // 12*8*64*8 bf16
    u16*   W2p   = W1p + 12 * 8 * 64 * 8;               // 2*4*8*64*8 bf16
    float* cvec  = (float*)(W2p + 2 * 4 * 8 * 64 * 8);  // [128] f32

    hipLaunchKernelGGL(const_kernel, dim3(1), dim3(DD), 0, stream,
                       tb, W2, b2, cvec);
    hipLaunchKernelGGL(pack_w, dim3(40), dim3(256), 0, stream,
                       W1, W2, W1p, W2p);
    hipLaunchKernelGGL(agg_kernel, dim3(N), dim3(DD), 0, stream,
                       nodef, ts, edgef, neighbors, edge_idxs, edge_times,
                       tw, tb, aggbf, nfbf);
    const int gb = (N + 31) / 32;
    hipLaunchKernelGGL(fused_gemm, dim3(gb), dim3(256), 0, stream,
                       aggbf, nfbf, W1p, W2p, b1, cvec, out, N);
}

// Round 3
// 480.385 us; speedup vs baseline: 1.3948x; 1.0841x over previous
//
#include <hip/hip_runtime.h>
#include <math.h>

#define DD 128            // feature dim
#define KNB 20            // neighbors per node
#define K3 384            // 3*D
#define NPB 8             // nodes per agg block

typedef unsigned short u16;
typedef __attribute__((ext_vector_type(8))) short short8;   // 8 bf16 = 4 VGPRs
typedef __attribute__((ext_vector_type(4))) float f32x4;

// f32 -> bf16 round-to-nearest-even
static __device__ __forceinline__ u16 f2bf(float x) {
    union { float f; unsigned u; } v; v.f = x;
    unsigned r = v.u + 0x7fffu + ((v.u >> 16) & 1u);
    return (u16)(r >> 16);
}

// fast cos: v_fract + v_cos_f32 (input in revolutions). Phase granularity at
// |x|~1e4 rad is ~1.2e-4 rev -> cos abs err ~7.5e-4, far below the bf16
// quantization (0.0625 at magnitude 20) already in the AGG path.
static __device__ __forceinline__ float fcos(float x) {
    float r = x * 0.15915494309189535f;       // 1/(2*pi)
    r = __builtin_amdgcn_fractf(r);
    return __builtin_amdgcn_cosf(r);
}

static __device__ __forceinline__ void st4bf(u16* p, float4 v) {
    ushort4 s;
    s.x = f2bf(v.x); s.y = f2bf(v.y); s.z = f2bf(v.z); s.w = f2bf(v.w);
    *(ushort4*)p = s;
}

// ---------------------------------------------------------------------------
// cvec[d] = b2[d] + sum_i cos(tb[i]) * W2[(2D+i)*D + d]   (src time emb const)
// ---------------------------------------------------------------------------
__global__ __launch_bounds__(DD) void const_kernel(
    const float* __restrict__ tb, const float* __restrict__ W2,
    const float* __restrict__ b2, float* __restrict__ cvec)
{
    int d = threadIdx.x;
    float acc = b2[d];
    #pragma unroll 8
    for (int i = 0; i < DD; ++i)
        acc = fmaf(cosf(tb[i]), W2[(size_t)(2 * DD + i) * DD + d], acc);
    cvec[d] = acc;
}

// ---------------------------------------------------------------------------
// Pack W1 (384x128) and W2 rows 0..255 into MFMA B-fragment order, bf16.
// For 16x16x32: lane L holds B[k0 + (L>>4)*8 + j][ct*16 + (L&15)], j=0..7,
// stored contiguously (16B per lane) at [ktile][ct][L][8].
// ---------------------------------------------------------------------------
__global__ __launch_bounds__(256) void pack_w(
    const float* __restrict__ W1, const float* __restrict__ W2,
    u16* __restrict__ W1p, u16* __restrict__ W2p)
{
    int t = blockIdx.x * 256 + threadIdx.x;
    if (t < 6144) {                       // W1: 12 * 8 * 64
        int L = t & 63;
        int ct = (t >> 6) & 7;
        int kt = t >> 9;
        int n  = ct * 16 + (L & 15);
        int kb = kt * 32 + (L >> 4) * 8;
        u16* d = W1p + (size_t)t * 8;
        #pragma unroll
        for (int j = 0; j < 8; ++j) d[j] = f2bf(W1[(size_t)(kb + j) * DD + n]);
    } else if (t < 10240) {               // W2 parts 0,1: 2 * 4 * 8 * 64
        int u = t - 6144;
        int L = u & 63;
        int ct = (u >> 6) & 7;
        int kt = (u >> 9) & 3;
        int part = u >> 11;
        int n  = ct * 16 + (L & 15);
        int kb = part * DD + kt * 32 + (L >> 4) * 8;
        u16* d = W2p + (size_t)u * 8;
        #pragma unroll
        for (int j = 0; j < 8; ++j) d[j] = f2bf(W2[(size_t)(kb + j) * DD + n]);
    }
}

// ---------------------------------------------------------------------------
// Kernel A v2: 8 nodes/block, 256 threads. thread = (nsub = tid>>5, c = tid&31).
// Row gathers are float4 (32 lanes x 16B = one 512B row). Indices/deltas staged
// to LDS once, read back as broadcasts. cos via v_fract+v_cos.
// Outputs bf16 AGG[N][384] and bf16 NF copy.
// ---------------------------------------------------------------------------
__global__ __launch_bounds__(256) void agg_kernel(
    const float* __restrict__ nodef, const float* __restrict__ ts,
    const float* __restrict__ edgef, const int* __restrict__ neighbors,
    const int* __restrict__ edge_idxs, const float* __restrict__ edge_times,
    const float* __restrict__ tw, const float* __restrict__ tb,
    u16* __restrict__ aggbf, u16* __restrict__ nfbf, int N)
{
    __shared__ int   s_nb[NPB * KNB];
    __shared__ int   s_eg[NPB * KNB];
    __shared__ float s_dt[NPB * KNB];

    const int tid = threadIdx.x;
    const int n0  = blockIdx.x * NPB;

    if (tid < NPB * KNB) {
        int nsub = tid / KNB;
        int k    = tid - nsub * KNB;
        int nn   = n0 + nsub;
        if (nn < N) {
            s_nb[tid] = neighbors[(size_t)nn * KNB + k];
            s_eg[tid] = edge_idxs[(size_t)nn * KNB + k];
            s_dt[tid] = ts[nn] - edge_times[(size_t)nn * KNB + k];
        } else {
            s_nb[tid] = 0; s_eg[tid] = 0; s_dt[tid] = 0.f;
        }
    }
    __syncthreads();

    const int c    = tid & 31;
    const int nsub = tid >> 5;
    const int n    = n0 + nsub;

    const float4* nf4 = (const float4*)nodef;
    const float4* ef4 = (const float4*)edgef;
    const float4  w4  = ((const float4*)tw)[c];
    const float4  b4  = ((const float4*)tb)[c];

    float4 an = make_float4(0.f, 0.f, 0.f, 0.f);
    float4 ae = an, at = an;

    const int*   nb  = s_nb + nsub * KNB;
    const int*   eg  = s_eg + nsub * KNB;
    const float* dtp = s_dt + nsub * KNB;

    #pragma unroll 10
    for (int k = 0; k < KNB; ++k) {
        int   ni = nb[k];
        int   ei = eg[k];
        float dt = dtp[k];
        float4 nv = nf4[(size_t)ni * 32 + c];
        float4 ev = ef4[(size_t)ei * 32 + c];
        an.x += nv.x; an.y += nv.y; an.z += nv.z; an.w += nv.w;
        ae.x += ev.x; ae.y += ev.y; ae.z += ev.z; ae.w += ev.w;
        at.x += fcos(fmaf(dt, w4.x, b4.x));
        at.y += fcos(fmaf(dt, w4.y, b4.y));
        at.z += fcos(fmaf(dt, w4.z, b4.z));
        at.w += fcos(fmaf(dt, w4.w, b4.w));
    }

    if (n < N) {
        u16* o = aggbf + (size_t)n * K3;
        st4bf(o + 4 * c,           an);
        st4bf(o + DD + 4 * c,      at);
        st4bf(o + 2 * DD + 4 * c,  ae);
        float4 sf = nf4[(size_t)n * 32 + c];
        st4bf(nfbf + (size_t)n * DD + 4 * c, sf);
    }
}

// ---------------------------------------------------------------------------
// Fused MFMA GEMM: 32 rows/block, 256 threads = 4 waves.
// Phase1: H = relu(AGG@W1 + 20*b1)  -> bf16 in LDS
// Phase2: out = H@W2[0:128] + NF@W2[128:256] + cvec
// ---------------------------------------------------------------------------
#define APITCH 392      // bf16 elems; 784B rows: 16B-aligned, stride==4 mod 32 banks
#define HPITCH 136      // 272B rows: 16B-aligned, stride==4 mod 32 banks

__global__ __launch_bounds__(256) void fused_gemm(
    const u16* __restrict__ aggbf, const u16* __restrict__ nfbf,
    const u16* __restrict__ W1p, const u16* __restrict__ W2p,
    const float* __restrict__ b1, const float* __restrict__ cvec,
    float* __restrict__ out, int N)
{
    __shared__ __align__(16) u16 As[32 * APITCH];   // 25088 B; reused for Hs+NFs

    const int tid  = threadIdx.x;
    const int lane = tid & 63;
    const int wave = tid >> 6;
    const int row0 = blockIdx.x * 32;
    const int m0     = (wave & 1) * 16;
    const int ctbase = (wave >> 1) * 4;
    const int l15  = lane & 15;
    const int quad = lane >> 4;

    // ---- stage AGG tile [32][384] bf16 -> LDS ----
    {
        const float4* ag4 = (const float4*)aggbf;   // 8 bf16 per float4
        #pragma unroll
        for (int i = 0; i < 6; ++i) {
            int idx = tid + i * 256;                // 0..1535 = 32*48
            int r = idx / 48, c = idx - r * 48;
            float4 v = make_float4(0.f, 0.f, 0.f, 0.f);
            int row = row0 + r;
            if (row < N) v = ag4[(size_t)row * 48 + c];
            *(float4*)&As[r * APITCH + c * 8] = v;
        }
    }
    __syncthreads();

    // ---- phase 1: AGG @ W1 ----
    f32x4 acc[4];
    #pragma unroll
    for (int c = 0; c < 4; ++c) acc[c] = (f32x4){0.f, 0.f, 0.f, 0.f};

    const short8* W1v = (const short8*)W1p;
    for (int kt = 0; kt < 12; ++kt) {
        short8 a = *(const short8*)&As[(m0 + l15) * APITCH + kt * 32 + quad * 8];
        #pragma unroll
        for (int c = 0; c < 4; ++c) {
            short8 b = W1v[(size_t)(kt * 8 + ctbase + c) * 64 + lane];
            acc[c] = __builtin_amdgcn_mfma_f32_16x16x32_bf16(a, b, acc[c], 0, 0, 0);
        }
    }
    __syncthreads();    // all waves done reading As

    // ---- epilogue 1: bias+relu -> Hs (bf16, reused LDS); stage NF tile ----
    u16* Hs  = As;
    u16* NFs = As + 32 * HPITCH;
    #pragma unroll
    for (int c = 0; c < 4; ++c) {
        int col = (ctbase + c) * 16 + l15;
        float bb = (float)KNB * b1[col];
        #pragma unroll
        for (int r = 0; r < 4; ++r) {
            float h = acc[c][r] + bb;               // C/D: col=lane&15, row=quad*4+r
            h = h > 0.f ? h : 0.f;
            Hs[(m0 + quad * 4 + r) * HPITCH + col] = f2bf(h);
        }
    }
    {
        const float4* nf4 = (const float4*)nfbf;
        #pragma unroll
        for (int i = 0; i < 2; ++i) {
            int idx = tid + i * 256;                // 0..511 = 32*16
            int r = idx >> 4, c = idx & 15;
            float4 v = make_float4(0.f, 0.f, 0.f, 0.f);
            int row = row0 + r;
            if (row < N) v = nf4[(size_t)row * 16 + c];
            *(float4*)&NFs[r * HPITCH + c * 8] = v;
        }
    }
    __syncthreads();

    // ---- phase 2: H@W2a + NF@W2b + cvec ----
    f32x4 acc2[4];
    #pragma unroll
    for (int c = 0; c < 4; ++c) {
        float cv = cvec[(ctbase + c) * 16 + l15];
        acc2[c] = (f32x4){cv, cv, cv, cv};
    }
    const short8* W2v = (const short8*)W2p;
    for (int kt = 0; kt < 4; ++kt) {
        short8 aH = *(const short8*)&Hs[(m0 + l15) * HPITCH + kt * 32 + quad * 8];
        #pragma unroll
        for (int c = 0; c < 4; ++c) {
            short8 b = W2v[(size_t)(kt * 8 + ctbase + c) * 64 + lane];
            acc2[c] = __builtin_amdgcn_mfma_f32_16x16x32_bf16(aH, b, acc2[c], 0, 0, 0);
        }
        short8 aN = *(const short8*)&NFs[(m0 + l15) * HPITCH + kt * 32 + quad * 8];
        #pragma unroll
        for (int c = 0; c < 4; ++c) {
            short8 b = W2v[(size_t)((4 + kt) * 8 + ctbase + c) * 64 + lane];
            acc2[c] = __builtin_amdgcn_mfma_f32_16x16x32_bf16(aN, b, acc2[c], 0, 0, 0);
        }
    }

    // ---- store ----
    #pragma unroll
    for (int c = 0; c < 4; ++c) {
        int col = (ctbase + c) * 16 + l15;
        #pragma unroll
        for (int r = 0; r < 4; ++r) {
            int row = row0 + m0 + quad * 4 + r;
            if (row < N) out[(size_t)row * DD + col] = acc2[c][r];
        }
    }
}

// ---------------------------------------------------------------------------
extern "C" void kernel_launch(void* const* d_in, const int* in_sizes, int n_in,
                              void* d_out, int out_size, void* d_ws, size_t ws_size,
                              hipStream_t stream)
{
    const float* nodef      = (const float*)d_in[0];
    const float* ts         = (const float*)d_in[1];
    const float* edgef      = (const float*)d_in[2];
    const int*   neighbors  = (const int*)d_in[3];
    const int*   edge_idxs  = (const int*)d_in[4];
    const float* edge_times = (const float*)d_in[5];
    const float* tw         = (const float*)d_in[6];
    const float* tb         = (const float*)d_in[7];
    const float* W1         = (const float*)d_in[8];
    const float* b1         = (const float*)d_in[9];
    const float* W2         = (const float*)d_in[10];
    const float* b2         = (const float*)d_in[11];
    float*       out        = (float*)d_out;

    const int N = in_sizes[1];          // 30000

    u16*   aggbf = (u16*)d_ws;                          // [N*384] bf16
    u16*   nfbf  = aggbf + (size_t)N * K3;              // [N*128] bf16
    u16*   W1p   = nfbf + (size_t)N * DD;               // 12*8*64*8 bf16
    u16*   W2p   = W1p + 12 * 8 * 64 * 8;               // 2*4*8*64*8 bf16
    float* cvec  = (float*)(W2p + 2 * 4 * 8 * 64 * 8);  // [128] f32

    hipLaunchKernelGGL(const_kernel, dim3(1), dim3(DD), 0, stream,
                       tb, W2, b2, cvec);
    hipLaunchKernelGGL(pack_w, dim3(40), dim3(256), 0, stream,
                       W1, W2, W1p, W2p);
    hipLaunchKernelGGL(agg_kernel, dim3((N + NPB - 1) / NPB), dim3(256), 0, stream,
                       nodef, ts, edgef, neighbors, edge_idxs, edge_times,
                       tw, tb, aggbf, nfbf, N);
    hipLaunchKernelGGL(fused_gemm, dim3((N + 31) / 32), dim3(256), 0, stream,
                       aggbf, nfbf, W1p, W2p, b1, cvec, out, N);
}